// Round 5
// baseline (233.954 us; speedup 1.0000x reference)
//
#include <hip/hip_runtime.h>
#include <hip/hip_bf16.h>
#include <math.h>

#define NN 50000
#define EE 800000
#define DD 128
#define SLOPE 0.2f

typedef __attribute__((ext_vector_type(8))) short short8;   // 8 bf16 (4 VGPRs)
typedef __attribute__((ext_vector_type(4))) float f32x4;    // MFMA acc

static __device__ __forceinline__ float wred_sum(float v) {
#pragma unroll
    for (int m = 1; m < 64; m <<= 1) v += __shfl_xor(v, m, 64);
    return v;
}

static __device__ __forceinline__ ushort f2bf(float f) {
    __hip_bfloat16 b = __float2bfloat16(f);
    return *reinterpret_cast<ushort*>(&b);
}
static __device__ __forceinline__ float bf2f(unsigned int u) {
    return __uint_as_float((u & 0xffffu) << 16);
}
static __device__ __forceinline__ void unpack8(const uint4& xp, float* xv) {
    xv[0] = bf2f(xp.x); xv[1] = bf2f(xp.x >> 16);
    xv[2] = bf2f(xp.y); xv[3] = bf2f(xp.y >> 16);
    xv[4] = bf2f(xp.z); xv[5] = bf2f(xp.z >> 16);
    xv[6] = bf2f(xp.w); xv[7] = bf2f(xp.w >> 16);
}

// ---------------- CSR build ----------------
__global__ void k_degree(const int* __restrict__ dstv, int* __restrict__ deg,
                         int* __restrict__ epos) {
    int i = blockIdx.x * blockDim.x + threadIdx.x;
    if (i < EE) epos[i] = atomicAdd(&deg[dstv[i]], 1);
}

__global__ void k_blocksum(const int* __restrict__ deg, int* __restrict__ bsum) {
    int t = threadIdx.x;
    int idx = blockIdx.x * 256 + t;
    int v = (idx < NN) ? deg[idx] : 0;
#pragma unroll
    for (int m = 1; m < 64; m <<= 1) v += __shfl_xor(v, m, 64);
    __shared__ int part[4];
    if ((t & 63) == 0) part[t >> 6] = v;
    __syncthreads();
    if (t == 0) bsum[blockIdx.x] = part[0] + part[1] + part[2] + part[3];
}

__global__ void k_scan_bsum(const int* __restrict__ bsum, int* __restrict__ boff, int nb) {
    __shared__ int sd[2][256];
    int t = threadIdx.x;
    int v = (t < nb) ? bsum[t] : 0;
    sd[0][t] = v;
    __syncthreads();
    int s = 0;
    for (int off = 1; off < 256; off <<= 1) {
        int x = sd[s][t];
        if (t >= off) x += sd[s][t - off];
        sd[s ^ 1][t] = x;
        s ^= 1;
        __syncthreads();
    }
    if (t < nb) boff[t] = sd[s][t] - v;  // exclusive
}

__global__ void k_scan_final(const int* __restrict__ deg, const int* __restrict__ boff,
                             int* __restrict__ offs) {
    __shared__ int sd[2][256];
    int t = threadIdx.x;
    int idx = blockIdx.x * 256 + t;
    int v = (idx < NN) ? deg[idx] : 0;
    sd[0][t] = v;
    __syncthreads();
    int s = 0;
    for (int off = 1; off < 256; off <<= 1) {
        int x = sd[s][t];
        if (t >= off) x += sd[s][t - off];
        sd[s ^ 1][t] = x;
        s ^= 1;
        __syncthreads();
    }
    int incl = sd[s][t];
    int base = boff[blockIdx.x];
    if (idx < NN) offs[idx + 1] = base + incl;
    if (idx == 0) offs[0] = 0;
}

__global__ void k_scatter(const int* __restrict__ srcv, const int* __restrict__ dstv,
                          const int* __restrict__ offs, const int* __restrict__ epos,
                          int* __restrict__ csr_src) {
    int i = blockIdx.x * blockDim.x + threadIdx.x;
    if (i < EE) csr_src[offs[dstv[i]] + epos[i]] = srcv[i];
}

// ---------------- weight convert: Wt[i][n][k] = bf16(W_i[k][n]) ----------------
__global__ __launch_bounds__(256) void k_wconvert(
    const float* __restrict__ W0, const float* __restrict__ W1, const float* __restrict__ W2,
    const float* __restrict__ W3, const float* __restrict__ W4, const float* __restrict__ W5,
    ushort* __restrict__ Wt) {
    int idx = blockIdx.x * 256 + threadIdx.x;  // 6*16384
    int i = idx >> 14;
    int r = idx & 16383;
    int n = r >> 7;
    int k = r & 127;
    const float* Ws[6] = {W0, W1, W2, W3, W4, W5};
    Wt[idx] = f2bf(Ws[i][k * DD + n]);
}

// ---------------- MFMA 3-matrix GEMM with LDS-staged weights ----------------
// block=256 (4 waves), each wave: 32 rows x 128 cols. K=128.
// XBF=0: X fp32 (convert inline). XBF=1: X bf16 (direct short8 loads).
// Outputs: O0b=xl bf16, O1b=xr bf16 (logit-only), O2=lin fp32.
template <int XBF>
__global__ __launch_bounds__(256) void k_gemm3m(
    const float* __restrict__ Xf,     // [NN][128] fp32   (XBF=0)
    const ushort* __restrict__ Xb,    // [NN][128] bf16   (XBF=1)
    const ushort* __restrict__ Wt,    // [3][128][128] bf16, [n][k] layout
    ushort* __restrict__ O0b,         // xl bf16
    ushort* __restrict__ O1b,         // xr bf16
    float* __restrict__ O2) {         // lin fp32
    __shared__ ushort wsh[128 * 136];  // +8 shorts/row pad -> balanced banks
    int t = threadIdx.x;
    int wid = t >> 6, lane = t & 63;
    int m0 = blockIdx.x * 128 + wid * 32;
    int qrow = lane & 15, kg = lane >> 4;

    // A fragments: 2 m-tiles x 4 k-steps
    short8 afrag[2][4];
#pragma unroll
    for (int mg = 0; mg < 2; mg++) {
#pragma unroll
        for (int ks = 0; ks < 4; ks++) {
            int row = m0 + mg * 16 + qrow;
            row = (row < NN) ? row : (NN - 1);  // clamp (stores predicated)
            if (XBF) {
                afrag[mg][ks] = *reinterpret_cast<const short8*>(
                    Xb + (size_t)row * DD + ks * 32 + kg * 8);
            } else {
                const float* p = Xf + (size_t)row * DD + ks * 32 + kg * 8;
                float4 u0 = *reinterpret_cast<const float4*>(p);
                float4 u1 = *reinterpret_cast<const float4*>(p + 4);
                short8 s;
                s[0] = (short)f2bf(u0.x); s[1] = (short)f2bf(u0.y);
                s[2] = (short)f2bf(u0.z); s[3] = (short)f2bf(u0.w);
                s[4] = (short)f2bf(u1.x); s[5] = (short)f2bf(u1.y);
                s[6] = (short)f2bf(u1.z); s[7] = (short)f2bf(u1.w);
                afrag[mg][ks] = s;
            }
        }
    }

    for (int w = 0; w < 3; w++) {
        __syncthreads();  // previous iter done reading wsh
        const ushort* Wb = Wt + (size_t)w * DD * DD;
#pragma unroll
        for (int i = 0; i < 8; i++) {
            int flat = i * 256 + t;       // 0..2047 chunks of 8 shorts
            int row = flat >> 4, ch = flat & 15;
            short8 v = *reinterpret_cast<const short8*>(Wb + row * DD + ch * 8);
            *reinterpret_cast<short8*>(&wsh[row * 136 + ch * 8]) = v;
        }
        __syncthreads();

        f32x4 acc[2][8];
#pragma unroll
        for (int mg = 0; mg < 2; mg++)
#pragma unroll
            for (int ng = 0; ng < 8; ng++) acc[mg][ng] = (f32x4)(0.f);

#pragma unroll
        for (int ks = 0; ks < 4; ks++) {
            short8 bfrag[8];
#pragma unroll
            for (int ng = 0; ng < 8; ng++)
                bfrag[ng] = *reinterpret_cast<const short8*>(
                    &wsh[(ng * 16 + qrow) * 136 + ks * 32 + kg * 8]);
#pragma unroll
            for (int mg = 0; mg < 2; mg++)
#pragma unroll
                for (int ng = 0; ng < 8; ng++)
                    acc[mg][ng] = __builtin_amdgcn_mfma_f32_16x16x32_bf16(
                        afrag[mg][ks], bfrag[ng], acc[mg][ng], 0, 0, 0);
        }

        // store: row = m0 + mg*16 + kg*4 + r, col = ng*16 + qrow
#pragma unroll
        for (int mg = 0; mg < 2; mg++) {
#pragma unroll
            for (int r = 0; r < 4; r++) {
                int row = m0 + mg * 16 + kg * 4 + r;
                if (row < NN) {
#pragma unroll
                    for (int ng = 0; ng < 8; ng++) {
                        int col = ng * 16 + qrow;
                        float v = acc[mg][ng][r];
                        if (w == 0) O0b[(size_t)row * DD + col] = f2bf(v);
                        else if (w == 1) O1b[(size_t)row * DD + col] = f2bf(v);
                        else O2[(size_t)row * DD + col] = v;
                    }
                }
            }
        }
    }
}

// ---------------- fused logits + softmax (no-max) + aggregate + combine (+relu) ----------------
// Persistent grid-stride; wave per dst node; quarter-wave (16 lanes x 8 cols) per edge;
// 2-deep software pipeline (4 rotating row buffers, 2 edges consumed per iter).
// OUTVEC=0: writes h as bf16. OUTVEC=1: fuses the three output-layer matvecs.
template <int OUTVEC>
__global__ __launch_bounds__(256, 8) void k_fused(
    const int* __restrict__ offs, const int* __restrict__ csr_src,
    const ushort* __restrict__ xlb,  // [NN][128] bf16 (messages + logit left)
    const ushort* __restrict__ xrb,  // [NN][128] bf16 (logit right)
    const float* __restrict__ att,
    const float* __restrict__ lin, const float* __restrict__ bb,
    const float* __restrict__ blin, ushort* __restrict__ houtb,
    const float* __restrict__ Wlo, const float* __restrict__ Wro,
    const float* __restrict__ Wlino, const float* __restrict__ blino,
    float* __restrict__ xlo, float* __restrict__ xro, float* __restrict__ lino,
    int nwaves) {
    int gwave = (blockIdx.x * blockDim.x + threadIdx.x) >> 6;
    int lane = threadIdx.x & 63;
    int q = lane >> 4;    // quarter 0..3
    int ql = lane & 15;
    int c0 = ql * 8;

    float av[8];
    {
        float4 a0 = *reinterpret_cast<const float4*>(att + c0);
        float4 a1 = *reinterpret_cast<const float4*>(att + c0 + 4);
        av[0] = a0.x; av[1] = a0.y; av[2] = a0.z; av[3] = a0.w;
        av[4] = a1.x; av[5] = a1.y; av[6] = a1.z; av[7] = a1.w;
    }

    for (int wid = gwave; wid < NN; wid += nwaves) {
        int start = offs[wid];
        int deg = offs[wid + 1] - start;

        float xrv[8];
        {
            uint4 xrp = *reinterpret_cast<const uint4*>(xrb + (size_t)wid * DD + c0);
            unpack8(xrp, xrv);
        }

        float ss = 0.f;
        float acc[8];
#pragma unroll
        for (int c = 0; c < 8; c++) acc[c] = 0.f;

        // 2-deep pipeline: buffers A,B in flight + C,D prefetched each iter.
        int j = q;
        int sA = (j < deg) ? csr_src[start + j] : 0;
        int sB = (j + 4 < deg) ? csr_src[start + j + 4] : 0;
        uint4 bufA = *reinterpret_cast<const uint4*>(xlb + (size_t)sA * DD + c0);
        uint4 bufB = *reinterpret_cast<const uint4*>(xlb + (size_t)sB * DD + c0);
        for (; j < deg; j += 8) {
            int sC = (j + 8 < deg) ? csr_src[start + j + 8] : 0;
            int sD = (j + 12 < deg) ? csr_src[start + j + 12] : 0;
            uint4 bufC = *reinterpret_cast<const uint4*>(xlb + (size_t)sC * DD + c0);
            uint4 bufD = *reinterpret_cast<const uint4*>(xlb + (size_t)sD * DD + c0);

            // consume A (edge j, always valid here)
            {
                float xv[8];
                unpack8(bufA, xv);
                float v = 0.f;
#pragma unroll
                for (int c = 0; c < 8; c++) {
                    float u = xv[c] + xrv[c];
                    v += fmaxf(u, SLOPE * u) * av[c];
                }
#pragma unroll
                for (int msk = 1; msk < 16; msk <<= 1) v += __shfl_xor(v, msk, 64);
                float p = __expf(v);
                ss += p;
#pragma unroll
                for (int c = 0; c < 8; c++) acc[c] += p * xv[c];
            }
            // consume B (edge j+4, predicated)
            {
                bool ok = (j + 4) < deg;
                float xv[8];
                unpack8(bufB, xv);
                float v = 0.f;
#pragma unroll
                for (int c = 0; c < 8; c++) {
                    float u = xv[c] + xrv[c];
                    v += fmaxf(u, SLOPE * u) * av[c];
                }
#pragma unroll
                for (int msk = 1; msk < 16; msk <<= 1) v += __shfl_xor(v, msk, 64);
                float p = ok ? __expf(v) : 0.f;
                ss += p;
#pragma unroll
                for (int c = 0; c < 8; c++) acc[c] += p * xv[c];
            }
            bufA = bufC;
            bufB = bufD;
        }

        // merge the 4 quarter-states (plain sums, no-max softmax)
#pragma unroll
        for (int msk = 16; msk < 64; msk <<= 1) {
            ss += __shfl_xor(ss, msk, 64);
#pragma unroll
            for (int c = 0; c < 8; c++) acc[c] += __shfl_xor(acc[c], msk, 64);
        }

        if (q == 0) {
            float inv = 1.f / (ss + 1e-16f);
            float4 l0 = *reinterpret_cast<const float4*>(lin + (size_t)wid * DD + c0);
            float4 l1 = *reinterpret_cast<const float4*>(lin + (size_t)wid * DD + c0 + 4);
            float4 b0 = *reinterpret_cast<const float4*>(bb + c0);
            float4 b1 = *reinterpret_cast<const float4*>(bb + c0 + 4);
            float4 bl0 = *reinterpret_cast<const float4*>(blin + c0);
            float4 bl1 = *reinterpret_cast<const float4*>(blin + c0 + 4);
            float lv[8] = {l0.x, l0.y, l0.z, l0.w, l1.x, l1.y, l1.z, l1.w};
            float bv[8] = {b0.x, b0.y, b0.z, b0.w, b1.x, b1.y, b1.z, b1.w};
            float blv[8] = {bl0.x, bl0.y, bl0.z, bl0.w, bl1.x, bl1.y, bl1.z, bl1.w};
            float o[8];
#pragma unroll
            for (int c = 0; c < 8; c++) o[c] = fmaxf(acc[c] * inv + bv[c] + lv[c] + blv[c], 0.f);

            if (!OUTVEC) {
                uint4 pk;
                pk.x = (unsigned)f2bf(o[0]) | ((unsigned)f2bf(o[1]) << 16);
                pk.y = (unsigned)f2bf(o[2]) | ((unsigned)f2bf(o[3]) << 16);
                pk.z = (unsigned)f2bf(o[4]) | ((unsigned)f2bf(o[5]) << 16);
                pk.w = (unsigned)f2bf(o[6]) | ((unsigned)f2bf(o[7]) << 16);
                *reinterpret_cast<uint4*>(houtb + (size_t)wid * DD + c0) = pk;
            } else {
                // fused output-layer matvecs: d = h . W (128-length dots)
                float4 w0a = *reinterpret_cast<const float4*>(Wlo + c0);
                float4 w0b = *reinterpret_cast<const float4*>(Wlo + c0 + 4);
                float4 w1a = *reinterpret_cast<const float4*>(Wro + c0);
                float4 w1b = *reinterpret_cast<const float4*>(Wro + c0 + 4);
                float4 w2a = *reinterpret_cast<const float4*>(Wlino + c0);
                float4 w2b = *reinterpret_cast<const float4*>(Wlino + c0 + 4);
                float wv0[8] = {w0a.x, w0a.y, w0a.z, w0a.w, w0b.x, w0b.y, w0b.z, w0b.w};
                float wv1[8] = {w1a.x, w1a.y, w1a.z, w1a.w, w1b.x, w1b.y, w1b.z, w1b.w};
                float wv2[8] = {w2a.x, w2a.y, w2a.z, w2a.w, w2b.x, w2b.y, w2b.z, w2b.w};
                float d0 = 0.f, d1 = 0.f, d2 = 0.f;
#pragma unroll
                for (int c = 0; c < 8; c++) {
                    d0 += o[c] * wv0[c];
                    d1 += o[c] * wv1[c];
                    d2 += o[c] * wv2[c];
                }
#pragma unroll
                for (int msk = 1; msk < 16; msk <<= 1) {
                    d0 += __shfl_xor(d0, msk, 64);
                    d1 += __shfl_xor(d1, msk, 64);
                    d2 += __shfl_xor(d2, msk, 64);
                }
                if (ql == 0) {
                    xlo[wid] = d0;
                    xro[wid] = d1;
                    lino[wid] = d2 + blino[0];
                }
            }
        }
    }
}

// ---------------- fused output-layer logits + softmax (no-max) + aggregate ----------------
__global__ __launch_bounds__(256) void k_aggout(
    const int* __restrict__ offs, const int* __restrict__ csr_src,
    const float* __restrict__ xlo, const float* __restrict__ xro,
    const float* __restrict__ atto, const float* __restrict__ lino,
    const float* __restrict__ bo, float* __restrict__ out) {
    int wid = (blockIdx.x * blockDim.x + threadIdx.x) >> 6;
    int lane = threadIdx.x & 63;
    if (wid >= NN) return;
    int start = offs[wid];
    int deg = offs[wid + 1] - start;
    float xro_w = xro[wid];
    float a0 = atto[0];

    float sl = 0.f, nl = 0.f;
    for (int j = lane; j < deg; j += 64) {
        int s = csr_src[start + j];
        float xs = xlo[s];
        float u = xs + xro_w;
        float e = fmaxf(u, SLOPE * u) * a0;
        float p = __expf(e);
        sl += p;
        nl += p * xs;
    }
    sl = wred_sum(sl);
    nl = wred_sum(nl);
    if (lane == 0) out[wid] = nl / (sl + 1e-16f) + bo[0] + lino[wid];
}

extern "C" void kernel_launch(void* const* d_in, const int* in_sizes, int n_in,
                              void* d_out, int out_size, void* d_ws, size_t ws_size,
                              hipStream_t stream) {
    const float* x = (const float*)d_in[0];
    const int* ei = (const int*)d_in[1];
    const int* srcv = ei;
    const int* dstv = ei + EE;
    const float* Wl1 = (const float*)d_in[2];
    const float* Wr1 = (const float*)d_in[3];
    const float* att1 = (const float*)d_in[4];
    const float* b1 = (const float*)d_in[5];
    const float* Wlin1 = (const float*)d_in[6];
    const float* blin1 = (const float*)d_in[7];
    const float* Wl2 = (const float*)d_in[8];
    const float* Wr2 = (const float*)d_in[9];
    const float* att2 = (const float*)d_in[10];
    const float* b2 = (const float*)d_in[11];
    const float* Wlin2 = (const float*)d_in[12];
    const float* blin2 = (const float*)d_in[13];
    const float* Wlo = (const float*)d_in[14];
    const float* Wro = (const float*)d_in[15];
    const float* atto = (const float*)d_in[16];
    const float* bo = (const float*)d_in[17];
    const float* Wlino = (const float*)d_in[18];
    const float* blino = (const float*)d_in[19];

    char* w = (char*)d_ws;
    auto alloc = [&](size_t bytes) {
        void* p = (void*)w;
        w += (bytes + 255) & ~(size_t)255;
        return p;
    };
    ushort* xlb = (ushort*)alloc((size_t)NN * DD * 2);   // bf16 messages
    ushort* xrb = (ushort*)alloc((size_t)NN * DD * 2);   // bf16 logit-right
    float* lin = (float*)alloc((size_t)NN * DD * 4);
    ushort* hb = (ushort*)alloc((size_t)NN * DD * 2);    // hidden state, bf16
    ushort* Wt = (ushort*)alloc((size_t)6 * DD * DD * 2);
    float* xlo = (float*)alloc((size_t)NN * 4);
    float* xro = (float*)alloc((size_t)NN * 4);
    float* lino = (float*)alloc((size_t)NN * 4);
    int* deg = (int*)alloc((size_t)NN * 4);
    int* offs = (int*)alloc((size_t)(NN + 1) * 4);
    int* bsum = (int*)alloc(256 * 4);
    int* boff = (int*)alloc(256 * 4);
    int* csr_src = (int*)alloc((size_t)(EE + 16) * 4);
    int* epos = (int*)alloc((size_t)EE * 4);

    const int NB = (NN + 255) / 256;  // 196

    // CSR build
    hipMemsetAsync(deg, 0, (size_t)NN * 4, stream);
    k_degree<<<(EE + 255) / 256, 256, 0, stream>>>(dstv, deg, epos);
    k_blocksum<<<NB, 256, 0, stream>>>(deg, bsum);
    k_scan_bsum<<<1, 256, 0, stream>>>(bsum, boff, NB);
    k_scan_final<<<NB, 256, 0, stream>>>(deg, boff, offs);
    k_scatter<<<(EE + 255) / 256, 256, 0, stream>>>(srcv, dstv, offs, epos, csr_src);

    // weights -> transposed bf16
    k_wconvert<<<(6 * DD * DD) / 256, 256, 0, stream>>>(Wl1, Wr1, Wlin1, Wl2, Wr2, Wlin2, Wt);

    const int GEMM_GRID = (NN + 127) / 128;          // 391
    const int NODE_GRID = (NN * 64 + 255) / 256;     // 12500
    const int PERS_BLOCKS = 2048;                    // 8192 waves = 32/CU
    const int PERS_WAVES = PERS_BLOCKS * 4;

    // layer 1
    k_gemm3m<0><<<GEMM_GRID, 256, 0, stream>>>(x, nullptr, Wt + (size_t)0 * 3 * DD * DD,
                                               xlb, xrb, lin);
    k_fused<0><<<PERS_BLOCKS, 256, 0, stream>>>(offs, csr_src, xlb, xrb, att1, lin, b1, blin1, hb,
                                                nullptr, nullptr, nullptr, nullptr,
                                                nullptr, nullptr, nullptr, PERS_WAVES);
    // layer 2 (+fused output matvecs)
    k_gemm3m<1><<<GEMM_GRID, 256, 0, stream>>>(nullptr, hb, Wt + (size_t)1 * 3 * DD * DD,
                                               xlb, xrb, lin);
    k_fused<1><<<PERS_BLOCKS, 256, 0, stream>>>(offs, csr_src, xlb, xrb, att2, lin, b2, blin2,
                                                nullptr, Wlo, Wro, Wlino, blino,
                                                xlo, xro, lino, PERS_WAVES);
    // output layer aggregation
    k_aggout<<<NODE_GRID, 256, 0, stream>>>(offs, csr_src, xlo, xro, atto, lino, bo, (float*)d_out);
}

// Round 6
// 223.190 us; speedup vs baseline: 1.0482x; 1.0482x over previous
//
#include <hip/hip_runtime.h>
#include <hip/hip_bf16.h>
#include <math.h>

#define NN 50000
#define EE 800000
#define DD 128
#define SLOPE 0.2f

typedef __attribute__((ext_vector_type(8))) short short8;   // 8 bf16 (4 VGPRs)
typedef __attribute__((ext_vector_type(4))) float f32x4;    // MFMA acc

static __device__ __forceinline__ float wred_sum(float v) {
#pragma unroll
    for (int m = 1; m < 64; m <<= 1) v += __shfl_xor(v, m, 64);
    return v;
}

static __device__ __forceinline__ ushort f2bf(float f) {
    __hip_bfloat16 b = __float2bfloat16(f);
    return *reinterpret_cast<ushort*>(&b);
}
static __device__ __forceinline__ float bf2f(unsigned int u) {
    return __uint_as_float((u & 0xffffu) << 16);
}
static __device__ __forceinline__ void unpack8(const uint4& xp, float* xv) {
    xv[0] = bf2f(xp.x); xv[1] = bf2f(xp.x >> 16);
    xv[2] = bf2f(xp.y); xv[3] = bf2f(xp.y >> 16);
    xv[4] = bf2f(xp.z); xv[5] = bf2f(xp.z >> 16);
    xv[6] = bf2f(xp.w); xv[7] = bf2f(xp.w >> 16);
}

// ---------------- CSR build ----------------
__global__ void k_degree(const int* __restrict__ dstv, int* __restrict__ deg,
                         int* __restrict__ epos) {
    int i = blockIdx.x * blockDim.x + threadIdx.x;
    if (i < EE) epos[i] = atomicAdd(&deg[dstv[i]], 1);
}

__global__ void k_blocksum(const int* __restrict__ deg, int* __restrict__ bsum) {
    int t = threadIdx.x;
    int idx = blockIdx.x * 256 + t;
    int v = (idx < NN) ? deg[idx] : 0;
#pragma unroll
    for (int m = 1; m < 64; m <<= 1) v += __shfl_xor(v, m, 64);
    __shared__ int part[4];
    if ((t & 63) == 0) part[t >> 6] = v;
    __syncthreads();
    if (t == 0) bsum[blockIdx.x] = part[0] + part[1] + part[2] + part[3];
}

__global__ void k_scan_bsum(const int* __restrict__ bsum, int* __restrict__ boff, int nb) {
    __shared__ int sd[2][256];
    int t = threadIdx.x;
    int v = (t < nb) ? bsum[t] : 0;
    sd[0][t] = v;
    __syncthreads();
    int s = 0;
    for (int off = 1; off < 256; off <<= 1) {
        int x = sd[s][t];
        if (t >= off) x += sd[s][t - off];
        sd[s ^ 1][t] = x;
        s ^= 1;
        __syncthreads();
    }
    if (t < nb) boff[t] = sd[s][t] - v;  // exclusive
}

__global__ void k_scan_final(const int* __restrict__ deg, const int* __restrict__ boff,
                             int* __restrict__ offs) {
    __shared__ int sd[2][256];
    int t = threadIdx.x;
    int idx = blockIdx.x * 256 + t;
    int v = (idx < NN) ? deg[idx] : 0;
    sd[0][t] = v;
    __syncthreads();
    int s = 0;
    for (int off = 1; off < 256; off <<= 1) {
        int x = sd[s][t];
        if (t >= off) x += sd[s][t - off];
        sd[s ^ 1][t] = x;
        s ^= 1;
        __syncthreads();
    }
    int incl = sd[s][t];
    int base = boff[blockIdx.x];
    if (idx < NN) offs[idx + 1] = base + incl;
    if (idx == 0) offs[0] = 0;
}

__global__ void k_scatter(const int* __restrict__ srcv, const int* __restrict__ dstv,
                          const int* __restrict__ offs, const int* __restrict__ epos,
                          int* __restrict__ csr_src) {
    int i = blockIdx.x * blockDim.x + threadIdx.x;
    if (i < EE) csr_src[offs[dstv[i]] + epos[i]] = srcv[i];
}

// ---------------- weight convert: Wt[i][n][k] = bf16(W_i[k][n]) ----------------
__global__ __launch_bounds__(256) void k_wconvert(
    const float* __restrict__ W0, const float* __restrict__ W1, const float* __restrict__ W2,
    const float* __restrict__ W3, const float* __restrict__ W4, const float* __restrict__ W5,
    ushort* __restrict__ Wt) {
    int idx = blockIdx.x * 256 + threadIdx.x;  // 6*16384
    int i = idx >> 14;
    int r = idx & 16383;
    int n = r >> 7;
    int k = r & 127;
    const float* Ws[6] = {W0, W1, W2, W3, W4, W5};
    Wt[idx] = f2bf(Ws[i][k * DD + n]);
}

// ---------------- MFMA 3-matrix GEMM with LDS-staged weights ----------------
// block=256 (4 waves), each wave: 32 rows x 128 cols. K=128.
// XBF=0: X fp32 (convert inline). XBF=1: X bf16 (direct short8 loads).
// Outputs all bf16: O0b=xl, O1b=xr, O2b=lin.
template <int XBF>
__global__ __launch_bounds__(256) void k_gemm3m(
    const float* __restrict__ Xf,     // [NN][128] fp32   (XBF=0)
    const ushort* __restrict__ Xb,    // [NN][128] bf16   (XBF=1)
    const ushort* __restrict__ Wt,    // [3][128][128] bf16, [n][k] layout
    ushort* __restrict__ O0b,         // xl bf16
    ushort* __restrict__ O1b,         // xr bf16
    ushort* __restrict__ O2b) {       // lin bf16
    __shared__ ushort wsh[128 * 136];  // +8 shorts/row pad -> balanced banks
    int t = threadIdx.x;
    int wid = t >> 6, lane = t & 63;
    int m0 = blockIdx.x * 128 + wid * 32;
    int qrow = lane & 15, kg = lane >> 4;

    // A fragments: 2 m-tiles x 4 k-steps
    short8 afrag[2][4];
#pragma unroll
    for (int mg = 0; mg < 2; mg++) {
#pragma unroll
        for (int ks = 0; ks < 4; ks++) {
            int row = m0 + mg * 16 + qrow;
            row = (row < NN) ? row : (NN - 1);  // clamp (stores predicated)
            if (XBF) {
                afrag[mg][ks] = *reinterpret_cast<const short8*>(
                    Xb + (size_t)row * DD + ks * 32 + kg * 8);
            } else {
                const float* p = Xf + (size_t)row * DD + ks * 32 + kg * 8;
                float4 u0 = *reinterpret_cast<const float4*>(p);
                float4 u1 = *reinterpret_cast<const float4*>(p + 4);
                short8 s;
                s[0] = (short)f2bf(u0.x); s[1] = (short)f2bf(u0.y);
                s[2] = (short)f2bf(u0.z); s[3] = (short)f2bf(u0.w);
                s[4] = (short)f2bf(u1.x); s[5] = (short)f2bf(u1.y);
                s[6] = (short)f2bf(u1.z); s[7] = (short)f2bf(u1.w);
                afrag[mg][ks] = s;
            }
        }
    }

    for (int w = 0; w < 3; w++) {
        __syncthreads();  // previous iter done reading wsh
        const ushort* Wb = Wt + (size_t)w * DD * DD;
#pragma unroll
        for (int i = 0; i < 8; i++) {
            int flat = i * 256 + t;       // 0..2047 chunks of 8 shorts
            int row = flat >> 4, ch = flat & 15;
            short8 v = *reinterpret_cast<const short8*>(Wb + row * DD + ch * 8);
            *reinterpret_cast<short8*>(&wsh[row * 136 + ch * 8]) = v;
        }
        __syncthreads();

        f32x4 acc[2][8];
#pragma unroll
        for (int mg = 0; mg < 2; mg++)
#pragma unroll
            for (int ng = 0; ng < 8; ng++) acc[mg][ng] = (f32x4)(0.f);

#pragma unroll
        for (int ks = 0; ks < 4; ks++) {
            short8 bfrag[8];
#pragma unroll
            for (int ng = 0; ng < 8; ng++)
                bfrag[ng] = *reinterpret_cast<const short8*>(
                    &wsh[(ng * 16 + qrow) * 136 + ks * 32 + kg * 8]);
#pragma unroll
            for (int mg = 0; mg < 2; mg++)
#pragma unroll
                for (int ng = 0; ng < 8; ng++)
                    acc[mg][ng] = __builtin_amdgcn_mfma_f32_16x16x32_bf16(
                        afrag[mg][ks], bfrag[ng], acc[mg][ng], 0, 0, 0);
        }

        // store: row = m0 + mg*16 + kg*4 + r, col = ng*16 + qrow
        ushort* Ob = (w == 0) ? O0b : (w == 1) ? O1b : O2b;
#pragma unroll
        for (int mg = 0; mg < 2; mg++) {
#pragma unroll
            for (int r = 0; r < 4; r++) {
                int row = m0 + mg * 16 + kg * 4 + r;
                if (row < NN) {
#pragma unroll
                    for (int ng = 0; ng < 8; ng++) {
                        int col = ng * 16 + qrow;
                        Ob[(size_t)row * DD + col] = f2bf(acc[mg][ng][r]);
                    }
                }
            }
        }
    }
}

// ---------------- fused logits + softmax (no-max) + aggregate + combine (+relu) ----------------
// Non-persistent; wave per dst node; quarter-wave (16 lanes x 8 cols) per edge; stride-4
// simple loop (empirically best: low VGPR, 1 gather in flight, non-persistent grid).
// OUTVEC=0: writes h as bf16. OUTVEC=1: fuses the three output-layer matvecs.
template <int OUTVEC>
__global__ __launch_bounds__(256) void k_fused(
    const int* __restrict__ offs, const int* __restrict__ csr_src,
    const ushort* __restrict__ xlb,  // [NN][128] bf16 (messages + logit left)
    const ushort* __restrict__ xrb,  // [NN][128] bf16 (logit right)
    const float* __restrict__ att,
    const ushort* __restrict__ linb, // [NN][128] bf16 (skip connection)
    const float* __restrict__ bb,
    const float* __restrict__ blin, ushort* __restrict__ houtb,
    const float* __restrict__ Wlo, const float* __restrict__ Wro,
    const float* __restrict__ Wlino, const float* __restrict__ blino,
    float* __restrict__ xlo, float* __restrict__ xro, float* __restrict__ lino) {
    int wid = (blockIdx.x * blockDim.x + threadIdx.x) >> 6;
    int lane = threadIdx.x & 63;
    if (wid >= NN) return;
    int q = lane >> 4;    // quarter 0..3
    int ql = lane & 15;
    int c0 = ql * 8;

    float av[8];
    {
        float4 a0 = *reinterpret_cast<const float4*>(att + c0);
        float4 a1 = *reinterpret_cast<const float4*>(att + c0 + 4);
        av[0] = a0.x; av[1] = a0.y; av[2] = a0.z; av[3] = a0.w;
        av[4] = a1.x; av[5] = a1.y; av[6] = a1.z; av[7] = a1.w;
    }
    float xrv[8];
    {
        uint4 xrp = *reinterpret_cast<const uint4*>(xrb + (size_t)wid * DD + c0);
        unpack8(xrp, xrv);
    }

    int start = offs[wid];
    int deg = offs[wid + 1] - start;

    float ss = 0.f;
    float acc[8];
#pragma unroll
    for (int c = 0; c < 8; c++) acc[c] = 0.f;

    for (int j = q; j < deg; j += 4) {
        int s = csr_src[start + j];
        uint4 xp = *reinterpret_cast<const uint4*>(xlb + (size_t)s * DD + c0);
        float xv[8];
        unpack8(xp, xv);
        float v = 0.f;
#pragma unroll
        for (int c = 0; c < 8; c++) {
            float u = xv[c] + xrv[c];
            v += fmaxf(u, SLOPE * u) * av[c];
        }
#pragma unroll
        for (int msk = 1; msk < 16; msk <<= 1) v += __shfl_xor(v, msk, 64);
        float p = __expf(v);
        ss += p;
#pragma unroll
        for (int c = 0; c < 8; c++) acc[c] += p * xv[c];
    }

    // merge the 4 quarter-states (plain sums, no-max softmax)
#pragma unroll
    for (int msk = 16; msk < 64; msk <<= 1) {
        ss += __shfl_xor(ss, msk, 64);
#pragma unroll
        for (int c = 0; c < 8; c++) acc[c] += __shfl_xor(acc[c], msk, 64);
    }

    if (q == 0) {
        float inv = 1.f / (ss + 1e-16f);
        float lv[8];
        {
            uint4 lp = *reinterpret_cast<const uint4*>(linb + (size_t)wid * DD + c0);
            unpack8(lp, lv);
        }
        float4 b0 = *reinterpret_cast<const float4*>(bb + c0);
        float4 b1 = *reinterpret_cast<const float4*>(bb + c0 + 4);
        float4 bl0 = *reinterpret_cast<const float4*>(blin + c0);
        float4 bl1 = *reinterpret_cast<const float4*>(blin + c0 + 4);
        float bv[8] = {b0.x, b0.y, b0.z, b0.w, b1.x, b1.y, b1.z, b1.w};
        float blv[8] = {bl0.x, bl0.y, bl0.z, bl0.w, bl1.x, bl1.y, bl1.z, bl1.w};
        float o[8];
#pragma unroll
        for (int c = 0; c < 8; c++) o[c] = fmaxf(acc[c] * inv + bv[c] + lv[c] + blv[c], 0.f);

        if (!OUTVEC) {
            uint4 pk;
            pk.x = (unsigned)f2bf(o[0]) | ((unsigned)f2bf(o[1]) << 16);
            pk.y = (unsigned)f2bf(o[2]) | ((unsigned)f2bf(o[3]) << 16);
            pk.z = (unsigned)f2bf(o[4]) | ((unsigned)f2bf(o[5]) << 16);
            pk.w = (unsigned)f2bf(o[6]) | ((unsigned)f2bf(o[7]) << 16);
            *reinterpret_cast<uint4*>(houtb + (size_t)wid * DD + c0) = pk;
        } else {
            // fused output-layer matvecs: d = h . W (128-length dots)
            float4 w0a = *reinterpret_cast<const float4*>(Wlo + c0);
            float4 w0b = *reinterpret_cast<const float4*>(Wlo + c0 + 4);
            float4 w1a = *reinterpret_cast<const float4*>(Wro + c0);
            float4 w1b = *reinterpret_cast<const float4*>(Wro + c0 + 4);
            float4 w2a = *reinterpret_cast<const float4*>(Wlino + c0);
            float4 w2b = *reinterpret_cast<const float4*>(Wlino + c0 + 4);
            float wv0[8] = {w0a.x, w0a.y, w0a.z, w0a.w, w0b.x, w0b.y, w0b.z, w0b.w};
            float wv1[8] = {w1a.x, w1a.y, w1a.z, w1a.w, w1b.x, w1b.y, w1b.z, w1b.w};
            float wv2[8] = {w2a.x, w2a.y, w2a.z, w2a.w, w2b.x, w2b.y, w2b.z, w2b.w};
            float d0 = 0.f, d1 = 0.f, d2 = 0.f;
#pragma unroll
            for (int c = 0; c < 8; c++) {
                d0 += o[c] * wv0[c];
                d1 += o[c] * wv1[c];
                d2 += o[c] * wv2[c];
            }
#pragma unroll
            for (int msk = 1; msk < 16; msk <<= 1) {
                d0 += __shfl_xor(d0, msk, 64);
                d1 += __shfl_xor(d1, msk, 64);
                d2 += __shfl_xor(d2, msk, 64);
            }
            if (ql == 0) {
                xlo[wid] = d0;
                xro[wid] = d1;
                lino[wid] = d2 + blino[0];
            }
        }
    }
}

// ---------------- fused output-layer logits + softmax (no-max) + aggregate ----------------
__global__ __launch_bounds__(256) void k_aggout(
    const int* __restrict__ offs, const int* __restrict__ csr_src,
    const float* __restrict__ xlo, const float* __restrict__ xro,
    const float* __restrict__ atto, const float* __restrict__ lino,
    const float* __restrict__ bo, float* __restrict__ out) {
    int wid = (blockIdx.x * blockDim.x + threadIdx.x) >> 6;
    int lane = threadIdx.x & 63;
    if (wid >= NN) return;
    int start = offs[wid];
    int deg = offs[wid + 1] - start;
    float xro_w = xro[wid];
    float a0 = atto[0];

    float sl = 0.f, nl = 0.f;
    for (int j = lane; j < deg; j += 64) {
        int s = csr_src[start + j];
        float xs = xlo[s];
        float u = xs + xro_w;
        float e = fmaxf(u, SLOPE * u) * a0;
        float p = __expf(e);
        sl += p;
        nl += p * xs;
    }
    sl = wred_sum(sl);
    nl = wred_sum(nl);
    if (lane == 0) out[wid] = nl / (sl + 1e-16f) + bo[0] + lino[wid];
}

extern "C" void kernel_launch(void* const* d_in, const int* in_sizes, int n_in,
                              void* d_out, int out_size, void* d_ws, size_t ws_size,
                              hipStream_t stream) {
    const float* x = (const float*)d_in[0];
    const int* ei = (const int*)d_in[1];
    const int* srcv = ei;
    const int* dstv = ei + EE;
    const float* Wl1 = (const float*)d_in[2];
    const float* Wr1 = (const float*)d_in[3];
    const float* att1 = (const float*)d_in[4];
    const float* b1 = (const float*)d_in[5];
    const float* Wlin1 = (const float*)d_in[6];
    const float* blin1 = (const float*)d_in[7];
    const float* Wl2 = (const float*)d_in[8];
    const float* Wr2 = (const float*)d_in[9];
    const float* att2 = (const float*)d_in[10];
    const float* b2 = (const float*)d_in[11];
    const float* Wlin2 = (const float*)d_in[12];
    const float* blin2 = (const float*)d_in[13];
    const float* Wlo = (const float*)d_in[14];
    const float* Wro = (const float*)d_in[15];
    const float* atto = (const float*)d_in[16];
    const float* bo = (const float*)d_in[17];
    const float* Wlino = (const float*)d_in[18];
    const float* blino = (const float*)d_in[19];

    char* w = (char*)d_ws;
    auto alloc = [&](size_t bytes) {
        void* p = (void*)w;
        w += (bytes + 255) & ~(size_t)255;
        return p;
    };
    ushort* xlb = (ushort*)alloc((size_t)NN * DD * 2);   // bf16 messages
    ushort* xrb = (ushort*)alloc((size_t)NN * DD * 2);   // bf16 logit-right
    ushort* linb = (ushort*)alloc((size_t)NN * DD * 2);  // bf16 skip
    ushort* hb = (ushort*)alloc((size_t)NN * DD * 2);    // hidden state, bf16
    ushort* Wt = (ushort*)alloc((size_t)6 * DD * DD * 2);
    float* xlo = (float*)alloc((size_t)NN * 4);
    float* xro = (float*)alloc((size_t)NN * 4);
    float* lino = (float*)alloc((size_t)NN * 4);
    int* deg = (int*)alloc((size_t)NN * 4);
    int* offs = (int*)alloc((size_t)(NN + 1) * 4);
    int* bsum = (int*)alloc(256 * 4);
    int* boff = (int*)alloc(256 * 4);
    int* csr_src = (int*)alloc((size_t)(EE + 16) * 4);
    int* epos = (int*)alloc((size_t)EE * 4);

    const int NB = (NN + 255) / 256;  // 196

    // CSR build
    hipMemsetAsync(deg, 0, (size_t)NN * 4, stream);
    k_degree<<<(EE + 255) / 256, 256, 0, stream>>>(dstv, deg, epos);
    k_blocksum<<<NB, 256, 0, stream>>>(deg, bsum);
    k_scan_bsum<<<1, 256, 0, stream>>>(bsum, boff, NB);
    k_scan_final<<<NB, 256, 0, stream>>>(deg, boff, offs);
    k_scatter<<<(EE + 255) / 256, 256, 0, stream>>>(srcv, dstv, offs, epos, csr_src);

    // weights -> transposed bf16
    k_wconvert<<<(6 * DD * DD) / 256, 256, 0, stream>>>(Wl1, Wr1, Wlin1, Wl2, Wr2, Wlin2, Wt);

    const int GEMM_GRID = (NN + 127) / 128;          // 391
    const int NODE_GRID = (NN * 64 + 255) / 256;     // 12500

    // layer 1
    k_gemm3m<0><<<GEMM_GRID, 256, 0, stream>>>(x, nullptr, Wt + (size_t)0 * 3 * DD * DD,
                                               xlb, xrb, linb);
    k_fused<0><<<NODE_GRID, 256, 0, stream>>>(offs, csr_src, xlb, xrb, att1, linb, b1, blin1, hb,
                                              nullptr, nullptr, nullptr, nullptr,
                                              nullptr, nullptr, nullptr);
    // layer 2 (+fused output matvecs)
    k_gemm3m<1><<<GEMM_GRID, 256, 0, stream>>>(nullptr, hb, Wt + (size_t)1 * 3 * DD * DD,
                                               xlb, xrb, linb);
    k_fused<1><<<NODE_GRID, 256, 0, stream>>>(offs, csr_src, xlb, xrb, att2, linb, b2, blin2,
                                              nullptr, Wlo, Wro, Wlino, blino,
                                              xlo, xro, lino);
    // output layer aggregation
    k_aggout<<<NODE_GRID, 256, 0, stream>>>(offs, csr_src, xlo, xro, atto, lino, bo, (float*)d_out);
}

// Round 8
// 203.494 us; speedup vs baseline: 1.1497x; 1.0968x over previous
//
#include <hip/hip_runtime.h>
#include <hip/hip_bf16.h>
#include <math.h>

#define NN 50000
#define EE 800000
#define DD 128
#define SLOPE 0.2f

typedef __attribute__((ext_vector_type(8))) short short8;   // 8 bf16 (4 VGPRs)
typedef __attribute__((ext_vector_type(4))) float f32x4;    // MFMA acc

static __device__ __forceinline__ float wred_sum(float v) {
#pragma unroll
    for (int m = 1; m < 64; m <<= 1) v += __shfl_xor(v, m, 64);
    return v;
}

static __device__ __forceinline__ ushort f2bf(float f) {
    __hip_bfloat16 b = __float2bfloat16(f);
    return *reinterpret_cast<ushort*>(&b);
}
static __device__ __forceinline__ float bf2f(unsigned int u) {
    return __uint_as_float((u & 0xffffu) << 16);
}
static __device__ __forceinline__ void unpack8(const uint4& xp, float* xv) {
    xv[0] = bf2f(xp.x); xv[1] = bf2f(xp.x >> 16);
    xv[2] = bf2f(xp.y); xv[3] = bf2f(xp.y >> 16);
    xv[4] = bf2f(xp.z); xv[5] = bf2f(xp.z >> 16);
    xv[6] = bf2f(xp.w); xv[7] = bf2f(xp.w >> 16);
}

// ---------------- CSR build ----------------
__global__ void k_degree(const int* __restrict__ dstv, int* __restrict__ deg,
                         int* __restrict__ epos) {
    int i = blockIdx.x * blockDim.x + threadIdx.x;
    if (i < EE) epos[i] = atomicAdd(&deg[dstv[i]], 1);
}

__global__ void k_blocksum(const int* __restrict__ deg, int* __restrict__ bsum) {
    int t = threadIdx.x;
    int idx = blockIdx.x * 256 + t;
    int v = (idx < NN) ? deg[idx] : 0;
#pragma unroll
    for (int m = 1; m < 64; m <<= 1) v += __shfl_xor(v, m, 64);
    __shared__ int part[4];
    if ((t & 63) == 0) part[t >> 6] = v;
    __syncthreads();
    if (t == 0) bsum[blockIdx.x] = part[0] + part[1] + part[2] + part[3];
}

__global__ void k_scan_bsum(const int* __restrict__ bsum, int* __restrict__ boff, int nb) {
    __shared__ int sd[2][256];
    int t = threadIdx.x;
    int v = (t < nb) ? bsum[t] : 0;
    sd[0][t] = v;
    __syncthreads();
    int s = 0;
    for (int off = 1; off < 256; off <<= 1) {
        int x = sd[s][t];
        if (t >= off) x += sd[s][t - off];
        sd[s ^ 1][t] = x;
        s ^= 1;
        __syncthreads();
    }
    if (t < nb) boff[t] = sd[s][t] - v;  // exclusive
}

__global__ void k_scan_final(const int* __restrict__ deg, const int* __restrict__ boff,
                             int* __restrict__ offs) {
    __shared__ int sd[2][256];
    int t = threadIdx.x;
    int idx = blockIdx.x * 256 + t;
    int v = (idx < NN) ? deg[idx] : 0;
    sd[0][t] = v;
    __syncthreads();
    int s = 0;
    for (int off = 1; off < 256; off <<= 1) {
        int x = sd[s][t];
        if (t >= off) x += sd[s][t - off];
        sd[s ^ 1][t] = x;
        s ^= 1;
        __syncthreads();
    }
    int incl = sd[s][t];
    int base = boff[blockIdx.x];
    if (idx < NN) offs[idx + 1] = base + incl;
    if (idx == 0) offs[0] = 0;
}

__global__ void k_scatter(const int* __restrict__ srcv, const int* __restrict__ dstv,
                          const int* __restrict__ offs, const int* __restrict__ epos,
                          int* __restrict__ csr_src) {
    int i = blockIdx.x * blockDim.x + threadIdx.x;
    if (i < EE) csr_src[offs[dstv[i]] + epos[i]] = srcv[i];
}

// ---------------- weight convert: Wt[i][n][k] = bf16(W_i[k][n]) ----------------
__global__ __launch_bounds__(256) void k_wconvert(
    const float* __restrict__ W0, const float* __restrict__ W1, const float* __restrict__ W2,
    const float* __restrict__ W3, const float* __restrict__ W4, const float* __restrict__ W5,
    ushort* __restrict__ Wt) {
    int idx = blockIdx.x * 256 + threadIdx.x;  // 6*16384
    int i = idx >> 14;
    int r = idx & 16383;
    int n = r >> 7;
    int k = r & 127;
    const float* Ws[6] = {W0, W1, W2, W3, W4, W5};
    Wt[idx] = f2bf(Ws[i][k * DD + n]);
}

// ---------------- MFMA 3-matrix GEMM with LDS-staged weights ----------------
// block=256 (4 waves), each wave: 32 rows x 128 cols. K=128. grid=(NN+127)/128.
// XBF=0: X fp32 (convert inline). XBF=1: X bf16 (direct short8 loads).
// Outputs all bf16: O0b=xl, O1b=xr, O2b=lin.  (verified round-6 version)
template <int XBF>
__global__ __launch_bounds__(256) void k_gemm3m(
    const float* __restrict__ Xf,     // [NN][128] fp32   (XBF=0)
    const ushort* __restrict__ Xb,    // [NN][128] bf16   (XBF=1)
    const ushort* __restrict__ Wt,    // [3][128][128] bf16, [n][k] layout
    ushort* __restrict__ O0b,         // xl bf16
    ushort* __restrict__ O1b,         // xr bf16
    ushort* __restrict__ O2b) {       // lin bf16
    __shared__ ushort wsh[128 * 136];  // +8 shorts/row pad -> balanced banks
    int t = threadIdx.x;
    int wid = t >> 6, lane = t & 63;
    int m0 = blockIdx.x * 128 + wid * 32;
    int qrow = lane & 15, kg = lane >> 4;

    // A fragments: 2 m-tiles x 4 k-steps
    short8 afrag[2][4];
#pragma unroll
    for (int mg = 0; mg < 2; mg++) {
#pragma unroll
        for (int ks = 0; ks < 4; ks++) {
            int row = m0 + mg * 16 + qrow;
            row = (row < NN) ? row : (NN - 1);  // clamp (stores predicated)
            if (XBF) {
                afrag[mg][ks] = *reinterpret_cast<const short8*>(
                    Xb + (size_t)row * DD + ks * 32 + kg * 8);
            } else {
                const float* p = Xf + (size_t)row * DD + ks * 32 + kg * 8;
                float4 u0 = *reinterpret_cast<const float4*>(p);
                float4 u1 = *reinterpret_cast<const float4*>(p + 4);
                short8 s;
                s[0] = (short)f2bf(u0.x); s[1] = (short)f2bf(u0.y);
                s[2] = (short)f2bf(u0.z); s[3] = (short)f2bf(u0.w);
                s[4] = (short)f2bf(u1.x); s[5] = (short)f2bf(u1.y);
                s[6] = (short)f2bf(u1.z); s[7] = (short)f2bf(u1.w);
                afrag[mg][ks] = s;
            }
        }
    }

    for (int w = 0; w < 3; w++) {
        __syncthreads();  // previous iter done reading wsh
        const ushort* Wb = Wt + (size_t)w * DD * DD;
#pragma unroll
        for (int i = 0; i < 8; i++) {
            int flat = i * 256 + t;       // 0..2047 chunks of 8 shorts
            int row = flat >> 4, ch = flat & 15;
            short8 v = *reinterpret_cast<const short8*>(Wb + row * DD + ch * 8);
            *reinterpret_cast<short8*>(&wsh[row * 136 + ch * 8]) = v;
        }
        __syncthreads();

        f32x4 acc[2][8];
#pragma unroll
        for (int mg = 0; mg < 2; mg++)
#pragma unroll
            for (int ng = 0; ng < 8; ng++) acc[mg][ng] = (f32x4)(0.f);

#pragma unroll
        for (int ks = 0; ks < 4; ks++) {
            short8 bfrag[8];
#pragma unroll
            for (int ng = 0; ng < 8; ng++)
                bfrag[ng] = *reinterpret_cast<const short8*>(
                    &wsh[(ng * 16 + qrow) * 136 + ks * 32 + kg * 8]);
#pragma unroll
            for (int mg = 0; mg < 2; mg++)
#pragma unroll
                for (int ng = 0; ng < 8; ng++)
                    acc[mg][ng] = __builtin_amdgcn_mfma_f32_16x16x32_bf16(
                        afrag[mg][ks], bfrag[ng], acc[mg][ng], 0, 0, 0);
        }

        // store: row = m0 + mg*16 + kg*4 + r, col = ng*16 + qrow
        ushort* Ob = (w == 0) ? O0b : (w == 1) ? O1b : O2b;
#pragma unroll
        for (int mg = 0; mg < 2; mg++) {
#pragma unroll
            for (int r = 0; r < 4; r++) {
                int row = m0 + mg * 16 + kg * 4 + r;
                if (row < NN) {
#pragma unroll
                    for (int ng = 0; ng < 8; ng++) {
                        int col = ng * 16 + qrow;
                        Ob[(size_t)row * DD + col] = f2bf(acc[mg][ng][r]);
                    }
                }
            }
        }
    }
}

// ---------------- fused logits + softmax (no-max) + aggregate + combine (+relu) ----------------
// Non-persistent; wave per dst node; quarter-wave (16 lanes x 8 cols) per edge.
// Edge indices preloaded in ONE coalesced load per 64-edge batch, broadcast via shfl.
// UNIFORM trip count across quarters (rounds = ceil(nb/4)): all 64 lanes execute every
// round, so the cross-quarter __shfl always has its source lane active (the round-7 bug
// was shfl-from-inactive-lane when nb%4 != 0). OOB edges predicated via p=0.
// OUTVEC=0: writes h as bf16. OUTVEC=1: fuses the three output-layer matvecs.
template <int OUTVEC>
__global__ __launch_bounds__(256) void k_fused(
    const int* __restrict__ offs, const int* __restrict__ csr_src,
    const ushort* __restrict__ xlb,  // [NN][128] bf16 (messages + logit left)
    const ushort* __restrict__ xrb,  // [NN][128] bf16 (logit right)
    const float* __restrict__ att,
    const ushort* __restrict__ linb, // [NN][128] bf16 (skip connection)
    const float* __restrict__ bb,
    const float* __restrict__ blin, ushort* __restrict__ houtb,
    const float* __restrict__ Wlo, const float* __restrict__ Wro,
    const float* __restrict__ Wlino, const float* __restrict__ blino,
    float* __restrict__ xlo, float* __restrict__ xro, float* __restrict__ lino) {
    int wid = (blockIdx.x * blockDim.x + threadIdx.x) >> 6;
    int lane = threadIdx.x & 63;
    if (wid >= NN) return;
    int q = lane >> 4;    // quarter 0..3
    int ql = lane & 15;
    int c0 = ql * 8;

    float av[8];
    {
        float4 a0 = *reinterpret_cast<const float4*>(att + c0);
        float4 a1 = *reinterpret_cast<const float4*>(att + c0 + 4);
        av[0] = a0.x; av[1] = a0.y; av[2] = a0.z; av[3] = a0.w;
        av[4] = a1.x; av[5] = a1.y; av[6] = a1.z; av[7] = a1.w;
    }
    float xrv[8];
    {
        uint4 xrp = *reinterpret_cast<const uint4*>(xrb + (size_t)wid * DD + c0);
        unpack8(xrp, xrv);
    }

    int start = offs[wid];
    int deg = offs[wid + 1] - start;

    float ss = 0.f;
    float acc[8];
#pragma unroll
    for (int c = 0; c < 8; c++) acc[c] = 0.f;

    for (int eb = 0; eb < deg; eb += 64) {
        int nb = min(64, deg - eb);
        // one coalesced index load for the whole batch; lanes >= nb hold 0 (valid row)
        int myidx = (lane < nb) ? csr_src[start + eb + lane] : 0;
        int rounds = (nb + 3) >> 2;
        for (int r = 0; r < rounds; r++) {
            int j = r * 4 + q;           // <= 63 always
            bool ok = j < nb;
            int s = __shfl(myidx, j, 64);  // all lanes active: well-defined
            uint4 xp = *reinterpret_cast<const uint4*>(xlb + (size_t)s * DD + c0);
            float xv[8];
            unpack8(xp, xv);
            float v = 0.f;
#pragma unroll
            for (int c = 0; c < 8; c++) {
                float u = xv[c] + xrv[c];
                v += fmaxf(u, SLOPE * u) * av[c];
            }
#pragma unroll
            for (int msk = 1; msk < 16; msk <<= 1) v += __shfl_xor(v, msk, 64);
            float p = ok ? __expf(v) : 0.f;
            ss += p;
#pragma unroll
            for (int c = 0; c < 8; c++) acc[c] += p * xv[c];
        }
    }

    // merge the 4 quarter-states (plain sums, no-max softmax)
#pragma unroll
    for (int msk = 16; msk < 64; msk <<= 1) {
        ss += __shfl_xor(ss, msk, 64);
#pragma unroll
        for (int c = 0; c < 8; c++) acc[c] += __shfl_xor(acc[c], msk, 64);
    }

    if (q == 0) {
        float inv = 1.f / (ss + 1e-16f);
        float lv[8];
        {
            uint4 lp = *reinterpret_cast<const uint4*>(linb + (size_t)wid * DD + c0);
            unpack8(lp, lv);
        }
        float4 b0 = *reinterpret_cast<const float4*>(bb + c0);
        float4 b1 = *reinterpret_cast<const float4*>(bb + c0 + 4);
        float4 bl0 = *reinterpret_cast<const float4*>(blin + c0);
        float4 bl1 = *reinterpret_cast<const float4*>(blin + c0 + 4);
        float bv[8] = {b0.x, b0.y, b0.z, b0.w, b1.x, b1.y, b1.z, b1.w};
        float blv[8] = {bl0.x, bl0.y, bl0.z, bl0.w, bl1.x, bl1.y, bl1.z, bl1.w};
        float o[8];
#pragma unroll
        for (int c = 0; c < 8; c++) o[c] = fmaxf(acc[c] * inv + bv[c] + lv[c] + blv[c], 0.f);

        if (!OUTVEC) {
            uint4 pk;
            pk.x = (unsigned)f2bf(o[0]) | ((unsigned)f2bf(o[1]) << 16);
            pk.y = (unsigned)f2bf(o[2]) | ((unsigned)f2bf(o[3]) << 16);
            pk.z = (unsigned)f2bf(o[4]) | ((unsigned)f2bf(o[5]) << 16);
            pk.w = (unsigned)f2bf(o[6]) | ((unsigned)f2bf(o[7]) << 16);
            *reinterpret_cast<uint4*>(houtb + (size_t)wid * DD + c0) = pk;
        } else {
            // fused output-layer matvecs: d = h . W (128-length dots)
            float4 w0a = *reinterpret_cast<const float4*>(Wlo + c0);
            float4 w0b = *reinterpret_cast<const float4*>(Wlo + c0 + 4);
            float4 w1a = *reinterpret_cast<const float4*>(Wro + c0);
            float4 w1b = *reinterpret_cast<const float4*>(Wro + c0 + 4);
            float4 w2a = *reinterpret_cast<const float4*>(Wlino + c0);
            float4 w2b = *reinterpret_cast<const float4*>(Wlino + c0 + 4);
            float wv0[8] = {w0a.x, w0a.y, w0a.z, w0a.w, w0b.x, w0b.y, w0b.z, w0b.w};
            float wv1[8] = {w1a.x, w1a.y, w1a.z, w1a.w, w1b.x, w1b.y, w1b.z, w1b.w};
            float wv2[8] = {w2a.x, w2a.y, w2a.z, w2a.w, w2b.x, w2b.y, w2b.z, w2b.w};
            float d0 = 0.f, d1 = 0.f, d2 = 0.f;
#pragma unroll
            for (int c = 0; c < 8; c++) {
                d0 += o[c] * wv0[c];
                d1 += o[c] * wv1[c];
                d2 += o[c] * wv2[c];
            }
#pragma unroll
            for (int msk = 1; msk < 16; msk <<= 1) {
                d0 += __shfl_xor(d0, msk, 64);
                d1 += __shfl_xor(d1, msk, 64);
                d2 += __shfl_xor(d2, msk, 64);
            }
            if (ql == 0) {
                xlo[wid] = d0;
                xro[wid] = d1;
                lino[wid] = d2 + blino[0];
            }
        }
    }
}

// ---------------- fused output-layer logits + softmax (no-max) + aggregate ----------------
__global__ __launch_bounds__(256) void k_aggout(
    const int* __restrict__ offs, const int* __restrict__ csr_src,
    const float* __restrict__ xlo, const float* __restrict__ xro,
    const float* __restrict__ atto, const float* __restrict__ lino,
    const float* __restrict__ bo, float* __restrict__ out) {
    int wid = (blockIdx.x * blockDim.x + threadIdx.x) >> 6;
    int lane = threadIdx.x & 63;
    if (wid >= NN) return;
    int start = offs[wid];
    int deg = offs[wid + 1] - start;
    float xro_w = xro[wid];
    float a0 = atto[0];

    float sl = 0.f, nl = 0.f;
    for (int j = lane; j < deg; j += 64) {
        int s = csr_src[start + j];
        float xs = xlo[s];
        float u = xs + xro_w;
        float e = fmaxf(u, SLOPE * u) * a0;
        float p = __expf(e);
        sl += p;
        nl += p * xs;
    }
    sl = wred_sum(sl);
    nl = wred_sum(nl);
    if (lane == 0) out[wid] = nl / (sl + 1e-16f) + bo[0] + lino[wid];
}

extern "C" void kernel_launch(void* const* d_in, const int* in_sizes, int n_in,
                              void* d_out, int out_size, void* d_ws, size_t ws_size,
                              hipStream_t stream) {
    const float* x = (const float*)d_in[0];
    const int* ei = (const int*)d_in[1];
    const int* srcv = ei;
    const int* dstv = ei + EE;
    const float* Wl1 = (const float*)d_in[2];
    const float* Wr1 = (const float*)d_in[3];
    const float* att1 = (const float*)d_in[4];
    const float* b1 = (const float*)d_in[5];
    const float* Wlin1 = (const float*)d_in[6];
    const float* blin1 = (const float*)d_in[7];
    const float* Wl2 = (const float*)d_in[8];
    const float* Wr2 = (const float*)d_in[9];
    const float* att2 = (const float*)d_in[10];
    const float* b2 = (const float*)d_in[11];
    const float* Wlin2 = (const float*)d_in[12];
    const float* blin2 = (const float*)d_in[13];
    const float* Wlo = (const float*)d_in[14];
    const float* Wro = (const float*)d_in[15];
    const float* atto = (const float*)d_in[16];
    const float* bo = (const float*)d_in[17];
    const float* Wlino = (const float*)d_in[18];
    const float* blino = (const float*)d_in[19];

    char* w = (char*)d_ws;
    auto alloc = [&](size_t bytes) {
        void* p = (void*)w;
        w += (bytes + 255) & ~(size_t)255;
        return p;
    };
    ushort* xlb = (ushort*)alloc((size_t)NN * DD * 2);   // bf16 messages
    ushort* xrb = (ushort*)alloc((size_t)NN * DD * 2);   // bf16 logit-right
    ushort* linb = (ushort*)alloc((size_t)NN * DD * 2);  // bf16 skip
    ushort* hb = (ushort*)alloc((size_t)NN * DD * 2);    // hidden state, bf16
    ushort* Wt = (ushort*)alloc((size_t)6 * DD * DD * 2);
    float* xlo = (float*)alloc((size_t)NN * 4);
    float* xro = (float*)alloc((size_t)NN * 4);
    float* lino = (float*)alloc((size_t)NN * 4);
    int* deg = (int*)alloc((size_t)NN * 4);
    int* offs = (int*)alloc((size_t)(NN + 1) * 4);
    int* bsum = (int*)alloc(256 * 4);
    int* boff = (int*)alloc(256 * 4);
    int* csr_src = (int*)alloc((size_t)(EE + 64) * 4);
    int* epos = (int*)alloc((size_t)EE * 4);

    const int NB = (NN + 255) / 256;  // 196

    // CSR build
    hipMemsetAsync(deg, 0, (size_t)NN * 4, stream);
    k_degree<<<(EE + 255) / 256, 256, 0, stream>>>(dstv, deg, epos);
    k_blocksum<<<NB, 256, 0, stream>>>(deg, bsum);
    k_scan_bsum<<<1, 256, 0, stream>>>(bsum, boff, NB);
    k_scan_final<<<NB, 256, 0, stream>>>(deg, boff, offs);
    k_scatter<<<(EE + 255) / 256, 256, 0, stream>>>(srcv, dstv, offs, epos, csr_src);

    // weights -> transposed bf16
    k_wconvert<<<(6 * DD * DD) / 256, 256, 0, stream>>>(Wl1, Wr1, Wlin1, Wl2, Wr2, Wlin2, Wt);

    const int GEMM_GRID = (NN + 127) / 128;          // 391
    const int NODE_GRID = (NN * 64 + 255) / 256;     // 12500

    // layer 1
    k_gemm3m<0><<<GEMM_GRID, 256, 0, stream>>>(x, nullptr, Wt + (size_t)0 * 3 * DD * DD,
                                               xlb, xrb, linb);
    k_fused<0><<<NODE_GRID, 256, 0, stream>>>(offs, csr_src, xlb, xrb, att1, linb, b1, blin1, hb,
                                              nullptr, nullptr, nullptr, nullptr,
                                              nullptr, nullptr, nullptr);
    // layer 2 (+fused output matvecs)
    k_gemm3m<1><<<GEMM_GRID, 256, 0, stream>>>(nullptr, hb, Wt + (size_t)1 * 3 * DD * DD,
                                               xlb, xrb, linb);
    k_fused<1><<<NODE_GRID, 256, 0, stream>>>(offs, csr_src, xlb, xrb, att2, linb, b2, blin2,
                                              nullptr, Wlo, Wro, Wlino, blino,
                                              xlo, xro, lino);
    // output layer aggregation
    k_aggout<<<NODE_GRID, 256, 0, stream>>>(offs, csr_src, xlo, xro, atto, lino, bo, (float*)d_out);
}

// Round 9
// 192.064 us; speedup vs baseline: 1.2181x; 1.0595x over previous
//
#include <hip/hip_runtime.h>
#include <hip/hip_bf16.h>
#include <math.h>

#define NN 50000
#define EE 800000
#define DD 128
#define SLOPE 0.2f

typedef __attribute__((ext_vector_type(8))) short short8;   // 8 bf16 (4 VGPRs)
typedef __attribute__((ext_vector_type(4))) float f32x4;    // MFMA acc

static __device__ __forceinline__ float wred_sum(float v) {
#pragma unroll
    for (int m = 1; m < 64; m <<= 1) v += __shfl_xor(v, m, 64);
    return v;
}

static __device__ __forceinline__ ushort f2bf(float f) {
    __hip_bfloat16 b = __float2bfloat16(f);
    return *reinterpret_cast<ushort*>(&b);
}
static __device__ __forceinline__ float bf2f(unsigned int u) {
    return __uint_as_float((u & 0xffffu) << 16);
}
static __device__ __forceinline__ void unpack8(const uint4& xp, float* xv) {
    xv[0] = bf2f(xp.x); xv[1] = bf2f(xp.x >> 16);
    xv[2] = bf2f(xp.y); xv[3] = bf2f(xp.y >> 16);
    xv[4] = bf2f(xp.z); xv[5] = bf2f(xp.z >> 16);
    xv[6] = bf2f(xp.w); xv[7] = bf2f(xp.w >> 16);
}

// ---------------- CSR build ----------------
__global__ void k_degree(const int* __restrict__ dstv, int* __restrict__ deg,
                         int* __restrict__ epos) {
    int i = blockIdx.x * blockDim.x + threadIdx.x;
    if (i < EE) epos[i] = atomicAdd(&deg[dstv[i]], 1);
}

__global__ void k_blocksum(const int* __restrict__ deg, int* __restrict__ bsum) {
    int t = threadIdx.x;
    int idx = blockIdx.x * 256 + t;
    int v = (idx < NN) ? deg[idx] : 0;
#pragma unroll
    for (int m = 1; m < 64; m <<= 1) v += __shfl_xor(v, m, 64);
    __shared__ int part[4];
    if ((t & 63) == 0) part[t >> 6] = v;
    __syncthreads();
    if (t == 0) bsum[blockIdx.x] = part[0] + part[1] + part[2] + part[3];
}

__global__ void k_scan_bsum(const int* __restrict__ bsum, int* __restrict__ boff, int nb) {
    __shared__ int sd[2][256];
    int t = threadIdx.x;
    int v = (t < nb) ? bsum[t] : 0;
    sd[0][t] = v;
    __syncthreads();
    int s = 0;
    for (int off = 1; off < 256; off <<= 1) {
        int x = sd[s][t];
        if (t >= off) x += sd[s][t - off];
        sd[s ^ 1][t] = x;
        s ^= 1;
        __syncthreads();
    }
    if (t < nb) boff[t] = sd[s][t] - v;  // exclusive
}

__global__ void k_scan_final(const int* __restrict__ deg, const int* __restrict__ boff,
                             int* __restrict__ offs) {
    __shared__ int sd[2][256];
    int t = threadIdx.x;
    int idx = blockIdx.x * 256 + t;
    int v = (idx < NN) ? deg[idx] : 0;
    sd[0][t] = v;
    __syncthreads();
    int s = 0;
    for (int off = 1; off < 256; off <<= 1) {
        int x = sd[s][t];
        if (t >= off) x += sd[s][t - off];
        sd[s ^ 1][t] = x;
        s ^= 1;
        __syncthreads();
    }
    int incl = sd[s][t];
    int base = boff[blockIdx.x];
    if (idx < NN) offs[idx + 1] = base + incl;
    if (idx == 0) offs[0] = 0;
}

__global__ void k_scatter(const int* __restrict__ srcv, const int* __restrict__ dstv,
                          const int* __restrict__ offs, const int* __restrict__ epos,
                          int* __restrict__ csr_src) {
    int i = blockIdx.x * blockDim.x + threadIdx.x;
    if (i < EE) csr_src[offs[dstv[i]] + epos[i]] = srcv[i];
}

// ---------------- weight convert: Wt[i][n][k] = bf16(W_i[k][n]) ----------------
__global__ __launch_bounds__(256) void k_wconvert(
    const float* __restrict__ W0, const float* __restrict__ W1, const float* __restrict__ W2,
    const float* __restrict__ W3, const float* __restrict__ W4, const float* __restrict__ W5,
    ushort* __restrict__ Wt) {
    int idx = blockIdx.x * 256 + threadIdx.x;  // 6*16384
    int i = idx >> 14;
    int r = idx & 16383;
    int n = r >> 7;
    int k = r & 127;
    const float* Ws[6] = {W0, W1, W2, W3, W4, W5};
    Wt[idx] = f2bf(Ws[i][k * DD + n]);
}

// ---------------- MFMA 3-matrix GEMM with LDS-staged weights ----------------
// block=256 (4 waves), each wave: 32 rows x 128 cols. K=128. grid=(NN+127)/128.
// XBF=0: X fp32 (convert inline). XBF=1: X bf16 (direct short8 loads).
// Outputs all bf16: O0b=xl, O1b=xr, O2b=lin.  (verified round-6 version)
template <int XBF>
__global__ __launch_bounds__(256) void k_gemm3m(
    const float* __restrict__ Xf,     // [NN][128] fp32   (XBF=0)
    const ushort* __restrict__ Xb,    // [NN][128] bf16   (XBF=1)
    const ushort* __restrict__ Wt,    // [3][128][128] bf16, [n][k] layout
    ushort* __restrict__ O0b,         // xl bf16
    ushort* __restrict__ O1b,         // xr bf16
    ushort* __restrict__ O2b) {       // lin bf16
    __shared__ ushort wsh[128 * 136];  // +8 shorts/row pad -> balanced banks
    int t = threadIdx.x;
    int wid = t >> 6, lane = t & 63;
    int m0 = blockIdx.x * 128 + wid * 32;
    int qrow = lane & 15, kg = lane >> 4;

    // A fragments: 2 m-tiles x 4 k-steps
    short8 afrag[2][4];
#pragma unroll
    for (int mg = 0; mg < 2; mg++) {
#pragma unroll
        for (int ks = 0; ks < 4; ks++) {
            int row = m0 + mg * 16 + qrow;
            row = (row < NN) ? row : (NN - 1);  // clamp (stores predicated)
            if (XBF) {
                afrag[mg][ks] = *reinterpret_cast<const short8*>(
                    Xb + (size_t)row * DD + ks * 32 + kg * 8);
            } else {
                const float* p = Xf + (size_t)row * DD + ks * 32 + kg * 8;
                float4 u0 = *reinterpret_cast<const float4*>(p);
                float4 u1 = *reinterpret_cast<const float4*>(p + 4);
                short8 s;
                s[0] = (short)f2bf(u0.x); s[1] = (short)f2bf(u0.y);
                s[2] = (short)f2bf(u0.z); s[3] = (short)f2bf(u0.w);
                s[4] = (short)f2bf(u1.x); s[5] = (short)f2bf(u1.y);
                s[6] = (short)f2bf(u1.z); s[7] = (short)f2bf(u1.w);
                afrag[mg][ks] = s;
            }
        }
    }

    for (int w = 0; w < 3; w++) {
        __syncthreads();  // previous iter done reading wsh
        const ushort* Wb = Wt + (size_t)w * DD * DD;
#pragma unroll
        for (int i = 0; i < 8; i++) {
            int flat = i * 256 + t;       // 0..2047 chunks of 8 shorts
            int row = flat >> 4, ch = flat & 15;
            short8 v = *reinterpret_cast<const short8*>(Wb + row * DD + ch * 8);
            *reinterpret_cast<short8*>(&wsh[row * 136 + ch * 8]) = v;
        }
        __syncthreads();

        f32x4 acc[2][8];
#pragma unroll
        for (int mg = 0; mg < 2; mg++)
#pragma unroll
            for (int ng = 0; ng < 8; ng++) acc[mg][ng] = (f32x4)(0.f);

#pragma unroll
        for (int ks = 0; ks < 4; ks++) {
            short8 bfrag[8];
#pragma unroll
            for (int ng = 0; ng < 8; ng++)
                bfrag[ng] = *reinterpret_cast<const short8*>(
                    &wsh[(ng * 16 + qrow) * 136 + ks * 32 + kg * 8]);
#pragma unroll
            for (int mg = 0; mg < 2; mg++)
#pragma unroll
                for (int ng = 0; ng < 8; ng++)
                    acc[mg][ng] = __builtin_amdgcn_mfma_f32_16x16x32_bf16(
                        afrag[mg][ks], bfrag[ng], acc[mg][ng], 0, 0, 0);
        }

        // store: row = m0 + mg*16 + kg*4 + r, col = ng*16 + qrow
        ushort* Ob = (w == 0) ? O0b : (w == 1) ? O1b : O2b;
#pragma unroll
        for (int mg = 0; mg < 2; mg++) {
#pragma unroll
            for (int r = 0; r < 4; r++) {
                int row = m0 + mg * 16 + kg * 4 + r;
                if (row < NN) {
#pragma unroll
                    for (int ng = 0; ng < 8; ng++) {
                        int col = ng * 16 + qrow;
                        Ob[(size_t)row * DD + col] = f2bf(acc[mg][ng][r]);
                    }
                }
            }
        }
    }
}

// ---------------- fused logits + softmax (no-max) + aggregate + combine (+relu) ----------------
// ONE WAVE PER BLOCK (block=64, grid=NN): no intra-block straggler coupling.
// Quarter-wave (16 lanes x 8 cols) per edge; coalesced index preload + shfl broadcast;
// uniform trip count (round-7 fix). LeakyReLU via lrelu(u)*a = 0.6*u*a + 0.4*|u|*a with
// av6/av4 precomputed and |u| as free VOP3 abs modifier: 5 ops/channel vs 6.
// OUTVEC=0: writes h as bf16. OUTVEC=1: fuses the three output-layer matvecs.
template <int OUTVEC>
__global__ __launch_bounds__(64) void k_fused(
    const int* __restrict__ offs, const int* __restrict__ csr_src,
    const ushort* __restrict__ xlb,  // [NN][128] bf16 (messages + logit left)
    const ushort* __restrict__ xrb,  // [NN][128] bf16 (logit right)
    const float* __restrict__ att,
    const ushort* __restrict__ linb, // [NN][128] bf16 (skip connection)
    const float* __restrict__ bb,
    const float* __restrict__ blin, ushort* __restrict__ houtb,
    const float* __restrict__ Wlo, const float* __restrict__ Wro,
    const float* __restrict__ Wlino, const float* __restrict__ blino,
    float* __restrict__ xlo, float* __restrict__ xro, float* __restrict__ lino) {
    int wid = blockIdx.x;              // one node per wave
    int lane = threadIdx.x;            // 0..63
    int q = lane >> 4;    // quarter 0..3
    int ql = lane & 15;
    int c0 = ql * 8;

    float av6[8], av4[8];
    {
        float4 a0 = *reinterpret_cast<const float4*>(att + c0);
        float4 a1 = *reinterpret_cast<const float4*>(att + c0 + 4);
        float av[8] = {a0.x, a0.y, a0.z, a0.w, a1.x, a1.y, a1.z, a1.w};
#pragma unroll
        for (int c = 0; c < 8; c++) {
            av6[c] = 0.6f * av[c];
            av4[c] = 0.4f * av[c];
        }
    }
    float xrv[8];
    {
        uint4 xrp = *reinterpret_cast<const uint4*>(xrb + (size_t)wid * DD + c0);
        unpack8(xrp, xrv);
    }

    int start = offs[wid];
    int deg = offs[wid + 1] - start;

    float ss = 0.f;
    float acc[8];
#pragma unroll
    for (int c = 0; c < 8; c++) acc[c] = 0.f;

    for (int eb = 0; eb < deg; eb += 64) {
        int nb = min(64, deg - eb);
        // one coalesced index load for the whole batch; lanes >= nb hold 0 (valid row)
        int myidx = (lane < nb) ? csr_src[start + eb + lane] : 0;
        int rounds = (nb + 3) >> 2;
        for (int r = 0; r < rounds; r++) {
            int j = r * 4 + q;           // <= 63 always
            bool ok = j < nb;
            int s = __shfl(myidx, j, 64);  // all lanes active: well-defined
            uint4 xp = *reinterpret_cast<const uint4*>(xlb + (size_t)s * DD + c0);
            float xv[8];
            unpack8(xp, xv);
            float v = 0.f;
#pragma unroll
            for (int c = 0; c < 8; c++) {
                float u = xv[c] + xrv[c];
                v = __builtin_fmaf(u, av6[c], v);
                v = __builtin_fmaf(__builtin_fabsf(u), av4[c], v);  // abs = free modifier
            }
#pragma unroll
            for (int msk = 1; msk < 16; msk <<= 1) v += __shfl_xor(v, msk, 64);
            float p = ok ? __expf(v) : 0.f;
            ss += p;
#pragma unroll
            for (int c = 0; c < 8; c++) acc[c] += p * xv[c];
        }
    }

    // merge the 4 quarter-states (plain sums, no-max softmax)
#pragma unroll
    for (int msk = 16; msk < 64; msk <<= 1) {
        ss += __shfl_xor(ss, msk, 64);
#pragma unroll
        for (int c = 0; c < 8; c++) acc[c] += __shfl_xor(acc[c], msk, 64);
    }

    if (q == 0) {
        float inv = 1.f / (ss + 1e-16f);
        float lv[8];
        {
            uint4 lp = *reinterpret_cast<const uint4*>(linb + (size_t)wid * DD + c0);
            unpack8(lp, lv);
        }
        float4 b0 = *reinterpret_cast<const float4*>(bb + c0);
        float4 b1 = *reinterpret_cast<const float4*>(bb + c0 + 4);
        float4 bl0 = *reinterpret_cast<const float4*>(blin + c0);
        float4 bl1 = *reinterpret_cast<const float4*>(blin + c0 + 4);
        float bv[8] = {b0.x, b0.y, b0.z, b0.w, b1.x, b1.y, b1.z, b1.w};
        float blv[8] = {bl0.x, bl0.y, bl0.z, bl0.w, bl1.x, bl1.y, bl1.z, bl1.w};
        float o[8];
#pragma unroll
        for (int c = 0; c < 8; c++) o[c] = fmaxf(acc[c] * inv + bv[c] + lv[c] + blv[c], 0.f);

        if (!OUTVEC) {
            uint4 pk;
            pk.x = (unsigned)f2bf(o[0]) | ((unsigned)f2bf(o[1]) << 16);
            pk.y = (unsigned)f2bf(o[2]) | ((unsigned)f2bf(o[3]) << 16);
            pk.z = (unsigned)f2bf(o[4]) | ((unsigned)f2bf(o[5]) << 16);
            pk.w = (unsigned)f2bf(o[6]) | ((unsigned)f2bf(o[7]) << 16);
            *reinterpret_cast<uint4*>(houtb + (size_t)wid * DD + c0) = pk;
        } else {
            // fused output-layer matvecs: d = h . W (128-length dots)
            float4 w0a = *reinterpret_cast<const float4*>(Wlo + c0);
            float4 w0b = *reinterpret_cast<const float4*>(Wlo + c0 + 4);
            float4 w1a = *reinterpret_cast<const float4*>(Wro + c0);
            float4 w1b = *reinterpret_cast<const float4*>(Wro + c0 + 4);
            float4 w2a = *reinterpret_cast<const float4*>(Wlino + c0);
            float4 w2b = *reinterpret_cast<const float4*>(Wlino + c0 + 4);
            float wv0[8] = {w0a.x, w0a.y, w0a.z, w0a.w, w0b.x, w0b.y, w0b.z, w0b.w};
            float wv1[8] = {w1a.x, w1a.y, w1a.z, w1a.w, w1b.x, w1b.y, w1b.z, w1b.w};
            float wv2[8] = {w2a.x, w2a.y, w2a.z, w2a.w, w2b.x, w2b.y, w2b.z, w2b.w};
            float d0 = 0.f, d1 = 0.f, d2 = 0.f;
#pragma unroll
            for (int c = 0; c < 8; c++) {
                d0 += o[c] * wv0[c];
                d1 += o[c] * wv1[c];
                d2 += o[c] * wv2[c];
            }
#pragma unroll
            for (int msk = 1; msk < 16; msk <<= 1) {
                d0 += __shfl_xor(d0, msk, 64);
                d1 += __shfl_xor(d1, msk, 64);
                d2 += __shfl_xor(d2, msk, 64);
            }
            if (ql == 0) {
                xlo[wid] = d0;
                xro[wid] = d1;
                lino[wid] = d2 + blino[0];
            }
        }
    }
}

// ---------------- fused output-layer logits + softmax (no-max) + aggregate ----------------
__global__ __launch_bounds__(256) void k_aggout(
    const int* __restrict__ offs, const int* __restrict__ csr_src,
    const float* __restrict__ xlo, const float* __restrict__ xro,
    const float* __restrict__ atto, const float* __restrict__ lino,
    const float* __restrict__ bo, float* __restrict__ out) {
    int wid = (blockIdx.x * blockDim.x + threadIdx.x) >> 6;
    int lane = threadIdx.x & 63;
    if (wid >= NN) return;
    int start = offs[wid];
    int deg = offs[wid + 1] - start;
    float xro_w = xro[wid];
    float a0 = atto[0];

    float sl = 0.f, nl = 0.f;
    for (int j = lane; j < deg; j += 64) {
        int s = csr_src[start + j];
        float xs = xlo[s];
        float u = xs + xro_w;
        float e = fmaxf(u, SLOPE * u) * a0;
        float p = __expf(e);
        sl += p;
        nl += p * xs;
    }
    sl = wred_sum(sl);
    nl = wred_sum(nl);
    if (lane == 0) out[wid] = nl / (sl + 1e-16f) + bo[0] + lino[wid];
}

extern "C" void kernel_launch(void* const* d_in, const int* in_sizes, int n_in,
                              void* d_out, int out_size, void* d_ws, size_t ws_size,
                              hipStream_t stream) {
    const float* x = (const float*)d_in[0];
    const int* ei = (const int*)d_in[1];
    const int* srcv = ei;
    const int* dstv = ei + EE;
    const float* Wl1 = (const float*)d_in[2];
    const float* Wr1 = (const float*)d_in[3];
    const float* att1 = (const float*)d_in[4];
    const float* b1 = (const float*)d_in[5];
    const float* Wlin1 = (const float*)d_in[6];
    const float* blin1 = (const float*)d_in[7];
    const float* Wl2 = (const float*)d_in[8];
    const float* Wr2 = (const float*)d_in[9];
    const float* att2 = (const float*)d_in[10];
    const float* b2 = (const float*)d_in[11];
    const float* Wlin2 = (const float*)d_in[12];
    const float* blin2 = (const float*)d_in[13];
    const float* Wlo = (const float*)d_in[14];
    const float* Wro = (const float*)d_in[15];
    const float* atto = (const float*)d_in[16];
    const float* bo = (const float*)d_in[17];
    const float* Wlino = (const float*)d_in[18];
    const float* blino = (const float*)d_in[19];

    char* w = (char*)d_ws;
    auto alloc = [&](size_t bytes) {
        void* p = (void*)w;
        w += (bytes + 255) & ~(size_t)255;
        return p;
    };
    ushort* xlb = (ushort*)alloc((size_t)NN * DD * 2);   // bf16 messages
    ushort* xrb = (ushort*)alloc((size_t)NN * DD * 2);   // bf16 logit-right
    ushort* linb = (ushort*)alloc((size_t)NN * DD * 2);  // bf16 skip
    ushort* hb = (ushort*)alloc((size_t)NN * DD * 2);    // hidden state, bf16
    ushort* Wt = (ushort*)alloc((size_t)6 * DD * DD * 2);
    float* xlo = (float*)alloc((size_t)NN * 4);
    float* xro = (float*)alloc((size_t)NN * 4);
    float* lino = (float*)alloc((size_t)NN * 4);
    int* deg = (int*)alloc((size_t)NN * 4);
    int* offs = (int*)alloc((size_t)(NN + 1) * 4);
    int* bsum = (int*)alloc(256 * 4);
    int* boff = (int*)alloc(256 * 4);
    int* csr_src = (int*)alloc((size_t)(EE + 64) * 4);
    int* epos = (int*)alloc((size_t)EE * 4);

    const int NB = (NN + 255) / 256;  // 196

    // CSR build
    hipMemsetAsync(deg, 0, (size_t)NN * 4, stream);
    k_degree<<<(EE + 255) / 256, 256, 0, stream>>>(dstv, deg, epos);
    k_blocksum<<<NB, 256, 0, stream>>>(deg, bsum);
    k_scan_bsum<<<1, 256, 0, stream>>>(bsum, boff, NB);
    k_scan_final<<<NB, 256, 0, stream>>>(deg, boff, offs);
    k_scatter<<<(EE + 255) / 256, 256, 0, stream>>>(srcv, dstv, offs, epos, csr_src);

    // weights -> transposed bf16
    k_wconvert<<<(6 * DD * DD) / 256, 256, 0, stream>>>(Wl1, Wr1, Wlin1, Wl2, Wr2, Wlin2, Wt);

    const int GEMM_GRID = (NN + 127) / 128;          // 391
    const int NODE_GRID = (NN * 64 + 255) / 256;     // 12500

    // layer 1
    k_gemm3m<0><<<GEMM_GRID, 256, 0, stream>>>(x, nullptr, Wt + (size_t)0 * 3 * DD * DD,
                                               xlb, xrb, linb);
    k_fused<0><<<NN, 64, 0, stream>>>(offs, csr_src, xlb, xrb, att1, linb, b1, blin1, hb,
                                      nullptr, nullptr, nullptr, nullptr,
                                      nullptr, nullptr, nullptr);
    // layer 2 (+fused output matvecs)
    k_gemm3m<1><<<GEMM_GRID, 256, 0, stream>>>(nullptr, hb, Wt + (size_t)1 * 3 * DD * DD,
                                               xlb, xrb, linb);
    k_fused<1><<<NN, 64, 0, stream>>>(offs, csr_src, xlb, xrb, att2, linb, b2, blin2,
                                      nullptr, Wlo, Wro, Wlino, blino,
                                      xlo, xro, lino);
    // output layer aggregation
    k_aggout<<<NODE_GRID, 256, 0, stream>>>(offs, csr_src, xlo, xro, atto, lino, bo, (float*)d_out);
}